// Round 8
// baseline (429.333 us; speedup 1.0000x reference)
//
#include <hip/hip_runtime.h>
#include <hip/hip_bf16.h>

typedef __bf16 bf16x8 __attribute__((ext_vector_type(8)));
typedef float f32x4 __attribute__((ext_vector_type(4)));

#define BATCH 65536
#define NL 256    // N_LSTM
#define NZ 1024   // 4*N_LSTM
#define FEAT 5
#define ROWS 32   // batch rows per block
#define KTOT 288  // 256 (h@U) + 32 (x@W folded: 5 real + 27 zero)
#define ASTRIDE 296  // A_sh row stride (bf16); 592B -> rotated banks, <=2-way
#define HSTR 72      // h_sh row stride (bf16)
#define CGRP 4       // col-groups per row tile (64 gate-cols each)

__device__ __forceinline__ unsigned short f2bf(float f) {
  __hip_bfloat16 h = __float2bfloat16(f);  // RTNE
  return __builtin_bit_cast(unsigned short, h);
}

__device__ __forceinline__ float sigm(float z) {
  return __builtin_amdgcn_rcpf(1.f + __builtin_amdgcn_exp2f(z * -1.4426950408889634f));
}

// U [256][1024] f32 -> Ut [1024][288] bf16 rows k=0..255 (transposed, k-contiguous)
__global__ __launch_bounds__(256) void k_prep(const float* __restrict__ U,
                                              unsigned short* __restrict__ Ut) {
  __shared__ float t[32][33];
  const int bk = blockIdx.x >> 5;
  const int bn = blockIdx.x & 31;
  const int r = threadIdx.x >> 5;
  const int c = threadIdx.x & 31;
#pragma unroll
  for (int i = 0; i < 4; ++i)
    t[r + 8 * i][c] = U[(size_t)(bk * 32 + r + 8 * i) * NZ + bn * 32 + c];
  __syncthreads();
#pragma unroll
  for (int i = 0; i < 4; ++i)
    Ut[(size_t)(bn * 32 + r + 8 * i) * KTOT + bk * 32 + c] = f2bf(t[c][r + 8 * i]);
}

// Ut k-rows 256..287 = [W(5); zeros] transposed; also WdTg [16][256] bf16.
__global__ __launch_bounds__(1024) void k_prepx(const float* __restrict__ W,
                                                const float* __restrict__ Wd,
                                                unsigned short* __restrict__ Ut,
                                                unsigned short* __restrict__ WdTg) {
  const int idx = blockIdx.x * 1024 + threadIdx.x;  // 32768
  const int n = idx >> 5;
  const int cc = idx & 31;
  Ut[(size_t)n * KTOT + 256 + cc] = (cc < FEAT) ? f2bf(W[(size_t)cc * NZ + n]) : (unsigned short)0;
  if (blockIdx.x < 4) {
    const int p = idx >> 8;
    const int j = idx & 255;
    WdTg[p * 256 + j] = (p < FEAT) ? f2bf(Wd[(size_t)j * FEAT + p]) : (unsigned short)0;
  }
}

// ABLATION: MODE 0=full, 1=no-logits, 3=no-c0/stores, 4=+no-B-loads, 5=stage-only
template <int MODE>
__global__ __launch_bounds__(256, 4) void k_lstm(
    const float* __restrict__ x, const float* __restrict__ h0,
    const float* __restrict__ c0, const float* __restrict__ b,
    const float* __restrict__ bd, const unsigned short* __restrict__ Ut,
    const unsigned short* __restrict__ WdTg, float* __restrict__ out) {
  float* out_logits = out;
  float* out_h = out + (size_t)BATCH * FEAT;
  float* out_c = out_h + (size_t)BATCH * NL;

  __shared__ __align__(16) unsigned short A_sh[ROWS * ASTRIDE];  // 18.9 KB
  __shared__ __align__(16) unsigned short h_sh[ROWS * HSTR];     // 4.6 KB

  const int tid = threadIdx.x;
  const int w = tid >> 6;
  const int l = tid & 63;
  const int lrow = l & 15;
  const int lk8 = (l >> 4) * 8;
  const int lq = (l >> 4) * 4;
  const int cg = blockIdx.x & 3;
  const int m0 = (blockIdx.x >> 2) * ROWS;
  const int jcol = cg * 64 + w * 16 + lrow;

  // ---- stage A tile (identical in all modes)
  float4 sv[8];
#pragma unroll
  for (int it = 0; it < 8; ++it) {
    const int fi = it * 256 + tid;
    const int row = fi >> 6, c4 = fi & 63;
    sv[it] = *reinterpret_cast<const float4*>(h0 + (size_t)(m0 + row) * NL + c4 * 4);
  }
  float xv[4];
#pragma unroll
  for (int it = 0; it < 4; ++it) {
    const int idx = it * 256 + tid;
    const int row = idx >> 5, cc = idx & 31;
    xv[it] = (cc < FEAT) ? x[(size_t)(m0 + row) * FEAT + cc] : 0.f;
  }
#pragma unroll
  for (int it = 0; it < 8; ++it) {
    const int fi = it * 256 + tid;
    const int row = fi >> 6, c4 = fi & 63;
    *reinterpret_cast<ushort4*>(&A_sh[row * ASTRIDE + c4 * 4]) =
        make_ushort4(f2bf(sv[it].x), f2bf(sv[it].y), f2bf(sv[it].z), f2bf(sv[it].w));
  }
#pragma unroll
  for (int it = 0; it < 4; ++it) {
    const int idx = it * 256 + tid;
    const int row = idx >> 5, cc = idx & 31;
    A_sh[row * ASTRIDE + 256 + cc] = f2bf(xv[it]);
  }
  __syncthreads();

  if constexpr (MODE == 5) {  // staging floor: keep LDS live, do nothing else
    float v0 = *reinterpret_cast<const float*>(&A_sh[(tid & 1023) * 4]);
    asm volatile("" ::"v"(v0));
    return;
  }

  float bb[4];
#pragma unroll
  for (int g = 0; g < 4; ++g) bb[g] = b[g * 256 + jcol];

  f32x4 acc[2][4];
#pragma unroll
  for (int r = 0; r < 2; ++r)
#pragma unroll
    for (int g = 0; g < 4; ++g) acc[r][g] = (f32x4){0.f, 0.f, 0.f, 0.f};

  const unsigned short* bp[4];
#pragma unroll
  for (int g = 0; g < 4; ++g) bp[g] = Ut + (size_t)(g * 256 + jcol) * KTOT + lk8;

  bf16x8 bbuf[3][4];
  if constexpr (MODE != 4) {
#pragma unroll
    for (int g = 0; g < 4; ++g) bbuf[0][g] = *reinterpret_cast<const bf16x8*>(bp[g]);
#pragma unroll
    for (int g = 0; g < 4; ++g) bbuf[1][g] = *reinterpret_cast<const bf16x8*>(bp[g] + 32);
  }

#pragma unroll
  for (int kk = 0; kk < 9; ++kk) {
    if constexpr (MODE != 4) {
      if (kk < 7) {
#pragma unroll
        for (int g = 0; g < 4; ++g)
          bbuf[(kk + 2) % 3][g] =
              *reinterpret_cast<const bf16x8*>(bp[g] + (kk + 2) * 32);
        __builtin_amdgcn_sched_group_barrier(0x20, 4, 0);  // VMEM_READ x4
      }
    }
    const bf16x8 af0 =
        *reinterpret_cast<const bf16x8*>(&A_sh[lrow * ASTRIDE + kk * 32 + lk8]);
    const bf16x8 af1 =
        *reinterpret_cast<const bf16x8*>(&A_sh[(16 + lrow) * ASTRIDE + kk * 32 + lk8]);
    __builtin_amdgcn_sched_group_barrier(0x100, 2, 0);  // DS_READ x2
    if constexpr (MODE == 4) {
#pragma unroll
      for (int g = 0; g < 4; ++g) {
        acc[0][g] = __builtin_amdgcn_mfma_f32_16x16x32_bf16(af0, af0, acc[0][g], 0, 0, 0);
        acc[1][g] = __builtin_amdgcn_mfma_f32_16x16x32_bf16(af1, af0, acc[1][g], 0, 0, 0);
      }
    } else {
#pragma unroll
      for (int g = 0; g < 4; ++g) {
        acc[0][g] = __builtin_amdgcn_mfma_f32_16x16x32_bf16(af0, bbuf[kk % 3][g], acc[0][g], 0, 0, 0);
        acc[1][g] = __builtin_amdgcn_mfma_f32_16x16x32_bf16(af1, bbuf[kk % 3][g], acc[1][g], 0, 0, 0);
      }
    }
    __builtin_amdgcn_sched_group_barrier(0x8, 8, 0);  // MFMA x8
  }

  float c0v[2][4];
  if constexpr (MODE <= 1) {
#pragma unroll
    for (int r = 0; r < 2; ++r)
#pragma unroll
      for (int v = 0; v < 4; ++v)
        c0v[r][v] = c0[(size_t)(m0 + r * 16 + lq + v) * NL + jcol];
  }

#pragma unroll
  for (int r = 0; r < 2; ++r) {
#pragma unroll
    for (int v = 0; v < 4; ++v) {
      const int mloc = r * 16 + lq + v;
      const size_t m = (size_t)m0 + mloc;
      const float zi = acc[r][0][v] + bb[0];
      const float zf = acc[r][1][v] + bb[1];
      const float zc = acc[r][2][v] + bb[2];
      const float zo = acc[r][3][v] + bb[3];
      const float ig = sigm(zi);
      const float fg = sigm(zf);
      const float og = sigm(zo);
      const float rc = fmaxf(zc, 0.f);
      const float c0x = (MODE <= 1) ? c0v[r][v] : 0.5f;
      const float cv = fg * c0x + ig * rc;
      const float hv = og * fmaxf(cv, 0.f);
      if constexpr (MODE <= 1) {
        out_c[m * NL + jcol] = cv;
        out_h[m * NL + jcol] = hv;
      } else {
        asm volatile("" ::"v"(cv), "v"(hv));  // keep alive, no store
      }
      if constexpr (MODE == 0) h_sh[mloc * HSTR + (w * 16 + lrow)] = f2bf(hv);
    }
  }

  if constexpr (MODE == 0) {
    __syncthreads();
    if (w < 2) {
      f32x4 lacc = (f32x4){0.f, 0.f, 0.f, 0.f};
#pragma unroll
      for (int kk2 = 0; kk2 < 2; ++kk2) {
        const bf16x8 ah = *reinterpret_cast<const bf16x8*>(
            &h_sh[(w * 16 + lrow) * HSTR + kk2 * 32 + lk8]);
        const bf16x8 bw = *reinterpret_cast<const bf16x8*>(
            &WdTg[lrow * 256 + cg * 64 + kk2 * 32 + lk8]);
        lacc = __builtin_amdgcn_mfma_f32_16x16x32_bf16(ah, bw, lacc, 0, 0, 0);
      }
      if (lrow < FEAT) {
        const float addv = (cg == 0) ? bd[lrow] : 0.f;
#pragma unroll
        for (int v = 0; v < 4; ++v)
          atomicAdd(&out_logits[(size_t)(m0 + w * 16 + lq + v) * FEAT + lrow],
                    lacc[v] + addv);
      }
    }
  }
}

extern "C" void kernel_launch(void* const* d_in, const int* in_sizes, int n_in,
                              void* d_out, int out_size, void* d_ws, size_t ws_size,
                              hipStream_t stream) {
  const float* x = (const float*)d_in[0];
  const float* h0 = (const float*)d_in[1];
  const float* c0 = (const float*)d_in[2];
  const float* W = (const float*)d_in[3];
  const float* U = (const float*)d_in[4];
  const float* b = (const float*)d_in[5];
  const float* Wd = (const float*)d_in[6];
  const float* bd = (const float*)d_in[7];
  unsigned short* Ut = (unsigned short*)d_ws;     // 576 KB
  unsigned short* WdTg = Ut + (size_t)NZ * KTOT;  // +8 KB

  k_prep<<<256, 256, 0, stream>>>(U, Ut);
  k_prepx<<<32, 1024, 0, stream>>>(W, Wd, Ut, WdTg);

  const int grid = (BATCH / ROWS) * CGRP;
  // ---- ablation dispatches (no d_out writes; timing via rocprof per-dispatch)
  k_lstm<5><<<grid, 256, 0, stream>>>(x, h0, c0, b, bd, Ut, WdTg, (float*)d_out);
  k_lstm<4><<<grid, 256, 0, stream>>>(x, h0, c0, b, bd, Ut, WdTg, (float*)d_out);
  k_lstm<3><<<grid, 256, 0, stream>>>(x, h0, c0, b, bd, Ut, WdTg, (float*)d_out);
  k_lstm<1><<<grid, 256, 0, stream>>>(x, h0, c0, b, bd, Ut, WdTg, (float*)d_out);
  // ---- real output
  hipMemsetAsync(d_out, 0, (size_t)BATCH * FEAT * sizeof(float), stream);
  k_lstm<0><<<grid, 256, 0, stream>>>(x, h0, c0, b, bd, Ut, WdTg, (float*)d_out);
}

// Round 9
// 146.949 us; speedup vs baseline: 2.9216x; 2.9216x over previous
//
#include <hip/hip_runtime.h>
#include <hip/hip_bf16.h>

typedef __bf16 bf16x8 __attribute__((ext_vector_type(8)));
typedef float f32x4 __attribute__((ext_vector_type(4)));

#define BATCH 65536
#define NL 256    // N_LSTM
#define NZ 1024   // 4*N_LSTM
#define FEAT 5
#define ROWS 32   // batch rows per block
#define KTOT 288  // 256 (h@U) + 32 (x@W folded: 5 real + 27 zero)
#define ASTRIDE 296  // A_sh row stride (bf16); 592B -> rotated banks, <=2-way
#define HSTR 72      // h_sh row stride (bf16)
#define CTSTR 68     // c_t/h_t row stride (f32); 272B: 16B-aligned rows, rotated banks
#define CGRP 4       // col-groups per row tile (64 gate-cols each)

__device__ __forceinline__ unsigned short f2bf(float f) {
  __hip_bfloat16 h = __float2bfloat16(f);  // RTNE
  return __builtin_bit_cast(unsigned short, h);
}

__device__ __forceinline__ float sigm(float z) {
  return __builtin_amdgcn_rcpf(1.f + __builtin_amdgcn_exp2f(z * -1.4426950408889634f));
}

// U [256][1024] f32 -> Ut [1024][288] bf16 rows k=0..255 (transposed, k-contiguous)
__global__ __launch_bounds__(256) void k_prep(const float* __restrict__ U,
                                              unsigned short* __restrict__ Ut) {
  __shared__ float t[32][33];
  const int bk = blockIdx.x >> 5;
  const int bn = blockIdx.x & 31;
  const int r = threadIdx.x >> 5;
  const int c = threadIdx.x & 31;
#pragma unroll
  for (int i = 0; i < 4; ++i)
    t[r + 8 * i][c] = U[(size_t)(bk * 32 + r + 8 * i) * NZ + bn * 32 + c];
  __syncthreads();
#pragma unroll
  for (int i = 0; i < 4; ++i)
    Ut[(size_t)(bn * 32 + r + 8 * i) * KTOT + bk * 32 + c] = f2bf(t[c][r + 8 * i]);
}

// Ut k-rows 256..287 = [W(5); zeros] transposed; also WdTg [16][256] bf16.
__global__ __launch_bounds__(1024) void k_prepx(const float* __restrict__ W,
                                                const float* __restrict__ Wd,
                                                unsigned short* __restrict__ Ut,
                                                unsigned short* __restrict__ WdTg) {
  const int idx = blockIdx.x * 1024 + threadIdx.x;  // 32768
  const int n = idx >> 5;
  const int cc = idx & 31;
  Ut[(size_t)n * KTOT + 256 + cc] = (cc < FEAT) ? f2bf(W[(size_t)cc * NZ + n]) : (unsigned short)0;
  if (blockIdx.x < 4) {
    const int p = idx >> 8;
    const int j = idx & 255;
    WdTg[p * 256 + j] = (p < FEAT) ? f2bf(Wd[(size_t)j * FEAT + p]) : (unsigned short)0;
  }
}

// 256 threads = 4 waves; block = 32 rows x 64 gate-cols (x4 gates).
// Wave w owns jcol = cg*64 + w*16 + lrow for all 4 gates (register-only fusion).
// Epilogue: gate results -> LDS (A_sh reused) -> fully-coalesced float4 stores.
__global__ __launch_bounds__(256, 4) void k_lstm(
    const float* __restrict__ x, const float* __restrict__ h0,
    const float* __restrict__ c0, const float* __restrict__ b,
    const float* __restrict__ bd, const unsigned short* __restrict__ Ut,
    const unsigned short* __restrict__ WdTg, float* __restrict__ out) {
  float* out_logits = out;
  float* out_h = out + (size_t)BATCH * FEAT;
  float* out_c = out_h + (size_t)BATCH * NL;

  __shared__ __align__(16) unsigned short A_sh[ROWS * ASTRIDE];  // 18.9 KB (reused)
  __shared__ __align__(16) unsigned short h_sh[ROWS * HSTR];     // 4.6 KB

  const int tid = threadIdx.x;
  const int w = tid >> 6;
  const int l = tid & 63;
  const int lrow = l & 15;
  const int lk8 = (l >> 4) * 8;
  const int lq = (l >> 4) * 4;
  const int cg = blockIdx.x & 3;
  const int m0 = (blockIdx.x >> 2) * ROWS;
  const int jcol = cg * 64 + w * 16 + lrow;
  const int wcol = w * 16 + lrow;  // col within this block's 64-col group

  // ---- stage A tile: h0 [32][256] f32 -> bf16 cols 0..255
  float4 sv[8];
#pragma unroll
  for (int it = 0; it < 8; ++it) {
    const int fi = it * 256 + tid;
    const int row = fi >> 6, c4 = fi & 63;
    sv[it] = *reinterpret_cast<const float4*>(h0 + (size_t)(m0 + row) * NL + c4 * 4);
  }
  float xv[4];
#pragma unroll
  for (int it = 0; it < 4; ++it) {
    const int idx = it * 256 + tid;
    const int row = idx >> 5, cc = idx & 31;
    xv[it] = (cc < FEAT) ? x[(size_t)(m0 + row) * FEAT + cc] : 0.f;
  }
#pragma unroll
  for (int it = 0; it < 8; ++it) {
    const int fi = it * 256 + tid;
    const int row = fi >> 6, c4 = fi & 63;
    *reinterpret_cast<ushort4*>(&A_sh[row * ASTRIDE + c4 * 4]) =
        make_ushort4(f2bf(sv[it].x), f2bf(sv[it].y), f2bf(sv[it].z), f2bf(sv[it].w));
  }
#pragma unroll
  for (int it = 0; it < 4; ++it) {
    const int idx = it * 256 + tid;
    const int row = idx >> 5, cc = idx & 31;
    A_sh[row * ASTRIDE + 256 + cc] = f2bf(xv[it]);
  }
  __syncthreads();

  // ---- c0 loads issued HERE: ~40us of k-loop below to hide their latency
  float c0v[2][4];
#pragma unroll
  for (int r = 0; r < 2; ++r)
#pragma unroll
    for (int v = 0; v < 4; ++v)
      c0v[r][v] = c0[(size_t)(m0 + r * 16 + lq + v) * NL + jcol];

  float bb[4];
#pragma unroll
  for (int g = 0; g < 4; ++g) bb[g] = b[g * 256 + jcol];

  // ---- k-loop: rotating register prefetch of B, issue order pinned
  f32x4 acc[2][4];
#pragma unroll
  for (int r = 0; r < 2; ++r)
#pragma unroll
    for (int g = 0; g < 4; ++g) acc[r][g] = (f32x4){0.f, 0.f, 0.f, 0.f};

  const unsigned short* bp[4];
#pragma unroll
  for (int g = 0; g < 4; ++g) bp[g] = Ut + (size_t)(g * 256 + jcol) * KTOT + lk8;

  bf16x8 bbuf[3][4];
#pragma unroll
  for (int g = 0; g < 4; ++g) bbuf[0][g] = *reinterpret_cast<const bf16x8*>(bp[g]);
#pragma unroll
  for (int g = 0; g < 4; ++g) bbuf[1][g] = *reinterpret_cast<const bf16x8*>(bp[g] + 32);

#pragma unroll
  for (int kk = 0; kk < 9; ++kk) {
    if (kk < 7) {
#pragma unroll
      for (int g = 0; g < 4; ++g)
        bbuf[(kk + 2) % 3][g] =
            *reinterpret_cast<const bf16x8*>(bp[g] + (kk + 2) * 32);
      __builtin_amdgcn_sched_group_barrier(0x20, 4, 0);  // VMEM_READ x4 first
    }
    const bf16x8 af0 =
        *reinterpret_cast<const bf16x8*>(&A_sh[lrow * ASTRIDE + kk * 32 + lk8]);
    const bf16x8 af1 =
        *reinterpret_cast<const bf16x8*>(&A_sh[(16 + lrow) * ASTRIDE + kk * 32 + lk8]);
    __builtin_amdgcn_sched_group_barrier(0x100, 2, 0);  // DS_READ x2
#pragma unroll
    for (int g = 0; g < 4; ++g) {
      acc[0][g] = __builtin_amdgcn_mfma_f32_16x16x32_bf16(af0, bbuf[kk % 3][g], acc[0][g], 0, 0, 0);
      acc[1][g] = __builtin_amdgcn_mfma_f32_16x16x32_bf16(af1, bbuf[kk % 3][g], acc[1][g], 0, 0, 0);
    }
    __builtin_amdgcn_sched_group_barrier(0x8, 8, 0);  // MFMA x8
  }

  __syncthreads();  // A_sh reads done -> safe to reuse as f32 c_t/h_t

  float* c_t = reinterpret_cast<float*>(A_sh);  // [32][68] f32 = 8.7 KB
  float* h_t = c_t + ROWS * CTSTR;              // [32][68] f32 = 8.7 KB

  // ---- gates: scattered LDS writes (cheap), no global scatter
#pragma unroll
  for (int r = 0; r < 2; ++r) {
#pragma unroll
    for (int v = 0; v < 4; ++v) {
      const int mloc = r * 16 + lq + v;
      const float zi = acc[r][0][v] + bb[0];
      const float zf = acc[r][1][v] + bb[1];
      const float zc = acc[r][2][v] + bb[2];
      const float zo = acc[r][3][v] + bb[3];
      const float ig = sigm(zi);
      const float fg = sigm(zf);
      const float og = sigm(zo);
      const float rc = fmaxf(zc, 0.f);
      const float cv = fg * c0v[r][v] + ig * rc;
      const float hv = og * fmaxf(cv, 0.f);
      c_t[mloc * CTSTR + wcol] = cv;
      h_t[mloc * CTSTR + wcol] = hv;
      h_sh[mloc * HSTR + wcol] = f2bf(hv);
    }
  }
  __syncthreads();

  // ---- fully-coalesced stores: 2 float4 per array per thread
#pragma unroll
  for (int it = 0; it < 2; ++it) {
    const int fi = it * 256 + tid;  // 512 float4 slots = 32 rows x 16
    const int row = fi >> 4, c4 = fi & 15;
    const float4 cv4 = *reinterpret_cast<const float4*>(&c_t[row * CTSTR + c4 * 4]);
    const float4 hv4 = *reinterpret_cast<const float4*>(&h_t[row * CTSTR + c4 * 4]);
    float* dst_c = out_c + (size_t)(m0 + row) * NL + cg * 64 + c4 * 4;
    float* dst_h = out_h + (size_t)(m0 + row) * NL + cg * 64 + c4 * 4;
    *reinterpret_cast<float4*>(dst_c) = cv4;
    *reinterpret_cast<float4*>(dst_h) = hv4;
  }

  // ---- partial logits over this block's 64 cols: waves 0,1; atomic accumulate
  if (w < 2) {
    f32x4 lacc = (f32x4){0.f, 0.f, 0.f, 0.f};
#pragma unroll
    for (int kk2 = 0; kk2 < 2; ++kk2) {
      const bf16x8 ah = *reinterpret_cast<const bf16x8*>(
          &h_sh[(w * 16 + lrow) * HSTR + kk2 * 32 + lk8]);
      const bf16x8 bw = *reinterpret_cast<const bf16x8*>(
          &WdTg[lrow * 256 + cg * 64 + kk2 * 32 + lk8]);
      lacc = __builtin_amdgcn_mfma_f32_16x16x32_bf16(ah, bw, lacc, 0, 0, 0);
    }
    if (lrow < FEAT) {
      const float addv = (cg == 0) ? bd[lrow] : 0.f;
#pragma unroll
      for (int v = 0; v < 4; ++v)
        atomicAdd(&out_logits[(size_t)(m0 + w * 16 + lq + v) * FEAT + lrow],
                  lacc[v] + addv);
    }
  }
}

extern "C" void kernel_launch(void* const* d_in, const int* in_sizes, int n_in,
                              void* d_out, int out_size, void* d_ws, size_t ws_size,
                              hipStream_t stream) {
  const float* x = (const float*)d_in[0];
  const float* h0 = (const float*)d_in[1];
  const float* c0 = (const float*)d_in[2];
  const float* W = (const float*)d_in[3];
  const float* U = (const float*)d_in[4];
  const float* b = (const float*)d_in[5];
  const float* Wd = (const float*)d_in[6];
  const float* bd = (const float*)d_in[7];
  unsigned short* Ut = (unsigned short*)d_ws;     // 576 KB
  unsigned short* WdTg = Ut + (size_t)NZ * KTOT;  // +8 KB

  k_prep<<<256, 256, 0, stream>>>(U, Ut);
  k_prepx<<<32, 1024, 0, stream>>>(W, Wd, Ut, WdTg);
  hipMemsetAsync(d_out, 0, (size_t)BATCH * FEAT * sizeof(float), stream);
  k_lstm<<<(BATCH / ROWS) * CGRP, 256, 0, stream>>>(x, h0, c0, b, bd, Ut, WdTg,
                                                    (float*)d_out);
}

// Round 10
// 130.189 us; speedup vs baseline: 3.2978x; 1.1287x over previous
//
#include <hip/hip_runtime.h>
#include <hip/hip_bf16.h>

typedef __bf16 bf16x8 __attribute__((ext_vector_type(8)));
typedef float f32x4 __attribute__((ext_vector_type(4)));

#define BATCH 65536
#define NL 256    // N_LSTM
#define NZ 1024   // 4*N_LSTM
#define FEAT 5
#define ROWS 64   // batch rows per block
#define COLS 128  // gate-cols per block (CGRP=2)
#define KTOT 288  // 256 (h@U) + 32 (x@W folded: 5 real + 27 zero)
#define ASTRIDE 296  // A_sh row stride (bf16); 592B -> rotated banks, <=2-way
#define HTSTR 132    // h_t row stride (f32); 528B -> rotated banks
#define CGRP 2

__device__ __forceinline__ unsigned short f2bf(float f) {
  __hip_bfloat16 h = __float2bfloat16(f);  // RTNE
  return __builtin_bit_cast(unsigned short, h);
}

__device__ __forceinline__ float sigm(float z) {
  return __builtin_amdgcn_rcpf(1.f + __builtin_amdgcn_exp2f(z * -1.4426950408889634f));
}

// U [256][1024] f32 -> Ut [1024][288] bf16 rows k=0..255 (transposed, k-contiguous)
__global__ __launch_bounds__(256) void k_prep(const float* __restrict__ U,
                                              unsigned short* __restrict__ Ut) {
  __shared__ float t[32][33];
  const int bk = blockIdx.x >> 5;
  const int bn = blockIdx.x & 31;
  const int r = threadIdx.x >> 5;
  const int c = threadIdx.x & 31;
#pragma unroll
  for (int i = 0; i < 4; ++i)
    t[r + 8 * i][c] = U[(size_t)(bk * 32 + r + 8 * i) * NZ + bn * 32 + c];
  __syncthreads();
#pragma unroll
  for (int i = 0; i < 4; ++i)
    Ut[(size_t)(bn * 32 + r + 8 * i) * KTOT + bk * 32 + c] = f2bf(t[c][r + 8 * i]);
}

// Ut k-rows 256..287 = [W(5); zeros] transposed; also WdTg [16][256] bf16.
__global__ __launch_bounds__(1024) void k_prepx(const float* __restrict__ W,
                                                const float* __restrict__ Wd,
                                                unsigned short* __restrict__ Ut,
                                                unsigned short* __restrict__ WdTg) {
  const int idx = blockIdx.x * 1024 + threadIdx.x;  // 32768
  const int n = idx >> 5;
  const int cc = idx & 31;
  Ut[(size_t)n * KTOT + 256 + cc] = (cc < FEAT) ? f2bf(W[(size_t)cc * NZ + n]) : (unsigned short)0;
  if (blockIdx.x < 4) {
    const int p = idx >> 8;
    const int j = idx & 255;
    WdTg[p * 256 + j] = (p < FEAT) ? f2bf(Wd[(size_t)j * FEAT + p]) : (unsigned short)0;
  }
}

// 512 threads = 8 waves; block = 64 rows x 128 gate-cols (x4 gates).
// Wave w owns jcol = cg*128 + w*16 + lrow for all 4 gates; acc[4][4] covers
// 64 rows -> 16 MFMA per K-step per wave (4x the old density per B-load).
__global__ __launch_bounds__(512, 4) void k_lstm(
    const float* __restrict__ x, const float* __restrict__ h0,
    const float* __restrict__ c0, const float* __restrict__ b,
    const float* __restrict__ bd, const unsigned short* __restrict__ Ut,
    const unsigned short* __restrict__ WdTg, float* __restrict__ out) {
  float* out_logits = out;
  float* out_h = out + (size_t)BATCH * FEAT;
  float* out_c = out_h + (size_t)BATCH * NL;

  __shared__ __align__(16) unsigned short A_sh[ROWS * ASTRIDE];  // 37.9 KB (reused)

  const int tid = threadIdx.x;
  const int w = tid >> 6;   // wave 0..7
  const int l = tid & 63;
  const int lrow = l & 15;
  const int lk8 = (l >> 4) * 8;
  const int lq = (l >> 4) * 4;
  const int cg = blockIdx.x & 1;
  const int m0 = (blockIdx.x >> 1) * ROWS;
  const int jcol = cg * COLS + w * 16 + lrow;  // gate col 0..255
  const int wcol = w * 16 + lrow;              // col within block 0..127

  // ---- stage A tile: h0 [64][256] f32 -> bf16 cols 0..255 (8 float4/thread)
  float4 sv[8];
#pragma unroll
  for (int it = 0; it < 8; ++it) {
    const int fi = it * 512 + tid;  // 4096 float4 = 64 rows x 64
    const int row = fi >> 6, c4 = fi & 63;
    sv[it] = *reinterpret_cast<const float4*>(h0 + (size_t)(m0 + row) * NL + c4 * 4);
  }
  float xv[4];
#pragma unroll
  for (int it = 0; it < 4; ++it) {
    const int idx = it * 512 + tid;  // 2048 = 64 rows x 32
    const int row = idx >> 5, cc = idx & 31;
    xv[it] = (cc < FEAT) ? x[(size_t)(m0 + row) * FEAT + cc] : 0.f;
  }
#pragma unroll
  for (int it = 0; it < 8; ++it) {
    const int fi = it * 512 + tid;
    const int row = fi >> 6, c4 = fi & 63;
    *reinterpret_cast<ushort4*>(&A_sh[row * ASTRIDE + c4 * 4]) =
        make_ushort4(f2bf(sv[it].x), f2bf(sv[it].y), f2bf(sv[it].z), f2bf(sv[it].w));
  }
#pragma unroll
  for (int it = 0; it < 4; ++it) {
    const int idx = it * 512 + tid;
    const int row = idx >> 5, cc = idx & 31;
    A_sh[row * ASTRIDE + 256 + cc] = f2bf(xv[it]);
  }
  __syncthreads();

  float bb[4];
#pragma unroll
  for (int g = 0; g < 4; ++g) bb[g] = b[g * 256 + jcol];

  // ---- k-loop: JIT B loads, 16 MFMA per kk
  f32x4 acc[4][4];  // [r: row 16-tile][g: gate]
#pragma unroll
  for (int r = 0; r < 4; ++r)
#pragma unroll
    for (int g = 0; g < 4; ++g) acc[r][g] = (f32x4){0.f, 0.f, 0.f, 0.f};

  const unsigned short* bp[4];
#pragma unroll
  for (int g = 0; g < 4; ++g) bp[g] = Ut + (size_t)(g * 256 + jcol) * KTOT + lk8;

#pragma unroll
  for (int kk = 0; kk < 9; ++kk) {
    bf16x8 bf[4];
#pragma unroll
    for (int g = 0; g < 4; ++g)
      bf[g] = *reinterpret_cast<const bf16x8*>(bp[g] + kk * 32);
    __builtin_amdgcn_sched_group_barrier(0x20, 4, 0);  // VMEM_READ x4 first
    bf16x8 af[4];
#pragma unroll
    for (int r = 0; r < 4; ++r)
      af[r] = *reinterpret_cast<const bf16x8*>(
          &A_sh[(r * 16 + lrow) * ASTRIDE + kk * 32 + lk8]);
    __builtin_amdgcn_sched_group_barrier(0x100, 4, 0);  // DS_READ x4
#pragma unroll
    for (int g = 0; g < 4; ++g)
#pragma unroll
      for (int r = 0; r < 4; ++r)
        acc[r][g] = __builtin_amdgcn_mfma_f32_16x16x32_bf16(af[r], bf[g], acc[r][g], 0, 0, 0);
    __builtin_amdgcn_sched_group_barrier(0x8, 16, 0);   // MFMA x16
  }

  // ---- c0 loads (64B-segment clean); latency partially covered by gate math
  float c0v[4][4];
#pragma unroll
  for (int r = 0; r < 4; ++r)
#pragma unroll
    for (int v = 0; v < 4; ++v)
      c0v[r][v] = c0[(size_t)(m0 + r * 16 + lq + v) * NL + jcol];

  // ---- gates; c stores direct (line-clean); h held in regs
  float hvs[4][4];
#pragma unroll
  for (int r = 0; r < 4; ++r) {
#pragma unroll
    for (int v = 0; v < 4; ++v) {
      const size_t m = (size_t)m0 + r * 16 + lq + v;
      const float zi = acc[r][0][v] + bb[0];
      const float zf = acc[r][1][v] + bb[1];
      const float zc = acc[r][2][v] + bb[2];
      const float zo = acc[r][3][v] + bb[3];
      const float ig = sigm(zi);
      const float fg = sigm(zf);
      const float og = sigm(zo);
      const float rc = fmaxf(zc, 0.f);
      const float cv = fg * c0v[r][v] + ig * rc;
      const float hv = og * fmaxf(cv, 0.f);
      out_c[m * NL + jcol] = cv;
      hvs[r][v] = hv;
    }
  }

  __syncthreads();  // all k-loop A_sh reads done -> reuse as f32 h_t

  float* h_t = reinterpret_cast<float*>(A_sh);  // [64][132] f32 = 33.8 KB
#pragma unroll
  for (int r = 0; r < 4; ++r)
#pragma unroll
    for (int v = 0; v < 4; ++v)
      h_t[(r * 16 + lq + v) * HTSTR + wcol] = hvs[r][v];
  __syncthreads();

  // ---- coalesced h stores: 4 float4/thread
#pragma unroll
  for (int it = 0; it < 4; ++it) {
    const int fi = it * 512 + tid;  // 2048 float4 = 64 rows x 32
    const int row = fi >> 5, c4 = fi & 31;
    const float4 hv4 = *reinterpret_cast<const float4*>(&h_t[row * HTSTR + c4 * 4]);
    *reinterpret_cast<float4*>(out_h + (size_t)(m0 + row) * NL + cg * COLS + c4 * 4) = hv4;
  }

  // ---- partial logits over this block's 128 cols: waves 0..3 (16 rows each)
  if (w < 4) {
    f32x4 lacc = (f32x4){0.f, 0.f, 0.f, 0.f};
#pragma unroll
    for (int kk2 = 0; kk2 < 4; ++kk2) {
      const float4 hlo = *reinterpret_cast<const float4*>(
          &h_t[(w * 16 + lrow) * HTSTR + kk2 * 32 + lk8]);
      const float4 hhi = *reinterpret_cast<const float4*>(
          &h_t[(w * 16 + lrow) * HTSTR + kk2 * 32 + lk8 + 4]);
      bf16x8 ah;
      ah[0] = (__bf16)hlo.x; ah[1] = (__bf16)hlo.y;
      ah[2] = (__bf16)hlo.z; ah[3] = (__bf16)hlo.w;
      ah[4] = (__bf16)hhi.x; ah[5] = (__bf16)hhi.y;
      ah[6] = (__bf16)hhi.z; ah[7] = (__bf16)hhi.w;
      const bf16x8 bw = *reinterpret_cast<const bf16x8*>(
          &WdTg[lrow * 256 + cg * COLS + kk2 * 32 + lk8]);
      lacc = __builtin_amdgcn_mfma_f32_16x16x32_bf16(ah, bw, lacc, 0, 0, 0);
    }
    if (lrow < FEAT) {
      const float addv = (cg == 0) ? bd[lrow] : 0.f;
#pragma unroll
      for (int v = 0; v < 4; ++v)
        atomicAdd(&out_logits[(size_t)(m0 + w * 16 + lq + v) * FEAT + lrow],
                  lacc[v] + addv);
    }
  }
}

extern "C" void kernel_launch(void* const* d_in, const int* in_sizes, int n_in,
                              void* d_out, int out_size, void* d_ws, size_t ws_size,
                              hipStream_t stream) {
  const float* x = (const float*)d_in[0];
  const float* h0 = (const float*)d_in[1];
  const float* c0 = (const float*)d_in[2];
  const float* W = (const float*)d_in[3];
  const float* U = (const float*)d_in[4];
  const float* b = (const float*)d_in[5];
  const float* Wd = (const float*)d_in[6];
  const float* bd = (const float*)d_in[7];
  unsigned short* Ut = (unsigned short*)d_ws;     // 576 KB
  unsigned short* WdTg = Ut + (size_t)NZ * KTOT;  // +8 KB

  k_prep<<<256, 256, 0, stream>>>(U, Ut);
  k_prepx<<<32, 1024, 0, stream>>>(W, Wd, Ut, WdTg);
  hipMemsetAsync(d_out, 0, (size_t)BATCH * FEAT * sizeof(float), stream);
  k_lstm<<<(BATCH / ROWS) * CGRP, 512, 0, stream>>>(x, h0, c0, b, bd, Ut, WdTg,
                                                    (float*)d_out);
}